// Round 13
// baseline (364.398 us; speedup 1.0000x reference)
//
#include <hip/hip_runtime.h>
#include <hip/hip_bf16.h>

typedef unsigned short ushort;
typedef unsigned int uint;
typedef unsigned long long u64;
typedef _Float16 f16;

#define NN 4096
#define PP 128
#define QQ 128
#define HD 256
#define KH 8
#define DD 64
#define KK 16384  // P*Q

typedef _Float16 f16x2 __attribute__((ext_vector_type(2)));
typedef _Float16 f16x4 __attribute__((ext_vector_type(4)));
typedef _Float16 f16x8 __attribute__((ext_vector_type(8)));
typedef __fp16 fp16x2 __attribute__((ext_vector_type(2)));
typedef float f32x4 __attribute__((ext_vector_type(4)));

// ---------------------------------------------------------------------------
// K0: split W and Wt fp32 -> f16 hi + f16 lo; zero x; convert xn/xp -> f16.
// ---------------------------------------------------------------------------
__global__ __launch_bounds__(256) void k0_split2(
    const float* __restrict__ W, const float* __restrict__ Wt,
    const float* __restrict__ xn, const float* __restrict__ xp,
    f16* __restrict__ hiW, f16* __restrict__ loW,
    f16* __restrict__ hiT, f16* __restrict__ loT,
    f16* __restrict__ xnh, f16* __restrict__ xph, float* __restrict__ xz) {
  const int tid = blockIdx.x * 256 + threadIdx.x;
  const int i = tid * 4;
  if (tid < (NN * HD) / 4)
    *(float4*)&xz[i] = make_float4(0.f, 0.f, 0.f, 0.f);
  // xn cvt: tids [262144, 393216); xp cvt: [393216, 524288)
  if (tid >= 262144 && tid < 393216) {
    const int o = (tid - 262144) * 4;
    const float4 v = *(const float4*)&xn[o];
    f16x4 h; h[0] = (f16)v.x; h[1] = (f16)v.y; h[2] = (f16)v.z; h[3] = (f16)v.w;
    *(f16x4*)&xnh[o] = h;
  } else if (tid >= 393216 && tid < 524288) {
    const int o = (tid - 393216) * 4;
    const float4 v = *(const float4*)&xp[o];
    f16x4 h; h[0] = (f16)v.x; h[1] = (f16)v.y; h[2] = (f16)v.z; h[3] = (f16)v.w;
    *(f16x4*)&xph[o] = h;
  }
  const float* src;
  f16 *hi, *lo;
  int off;
  if (i < HD * PP * QQ) { src = W; hi = hiW; lo = loW; off = i; }
  else { src = Wt; hi = hiT; lo = loT; off = i - HD * PP * QQ; }
  const float4 w = *(const float4*)&src[off];
  const float wf[4] = {w.x, w.y, w.z, w.w};
  f16x4 hv, lv;
#pragma unroll
  for (int j = 0; j < 4; ++j) {
    const f16 h = (f16)wf[j];
    hv[j] = h;
    lv[j] = (f16)(wf[j] - (float)h);
  }
  *(f16x4*)&hi[off] = hv;
  *(f16x4*)&lo[off] = lv;
}

// ---------------------------------------------------------------------------
// K1: bilinear, BARRIER-FREE. Block 256n x 64h (4 waves, each a private 64n
// strip x full 64h). W -> VGPRs via per-lane loads (no global_load_lds, no
// drain); z wave-private in LDS (same-wave DS ordering, no __syncthreads).
// BK=32, K-split 16, h-split 4 -> grid (16,16,4) = 1024 blocks.
// ---------------------------------------------------------------------------
__global__ __launch_bounds__(256, 3) void k1_bilinear(
    const f16* __restrict__ xph, const f16* __restrict__ xnh,
    const f16* __restrict__ Whi, const f16* __restrict__ Wlo,
    float* __restrict__ xout) {
  __shared__ f16 zhi[256 * 40];   // wave w owns rows [w*64, w*64+64)  (20 KB)

  const int t = threadIdx.x;
  const int n0 = blockIdx.x * 256;
  const int kb = blockIdx.y * 1024;
  const int h0 = blockIdx.z * 64;
  const int pb = kb >> 7;         // 8 p values per K chunk

  const int l = t & 63, w = t >> 6;
  const int nrow = n0 + t;        // this lane's z row

  int aoff[4];
#pragma unroll
  for (int i = 0; i < 4; ++i)
    aoff[i] = (w * 64 + i * 16 + (l & 15)) * 40 + (l >> 4) * 8;

  const f16* bb_hi = Whi + (size_t)(h0 + (l & 15)) * KK + kb + (l >> 4) * 8;
  const f16* bb_lo = Wlo + (size_t)(h0 + (l & 15)) * KK + kb + (l >> 4) * 8;
  const f16* xnr = xnh + (size_t)nrow * QQ;
  const f16* xpr = xph + (size_t)nrow * PP + pb;

  f32x4 acc[4][4];
#pragma unroll
  for (int i = 0; i < 4; ++i)
#pragma unroll
    for (int j = 0; j < 4; ++j) acc[i][j] = (f32x4)0.f;

  for (int pl = 0; pl < 8; ++pl) {
    const f16 xpv = xpr[pl];
    f16x8 xb;
#pragma unroll
    for (int m = 0; m < 8; ++m) xb[m] = xpv;
#pragma unroll
    for (int qc = 0; qc < 4; ++qc) {
      const int c = pl * 4 + qc;
      const int kc = c * 32;

      // B fragments -> VGPRs (issue first; vmcnt-scoreboarded, pipelined)
      f16x8 Bh[4], Bl[4];
#pragma unroll
      for (int j = 0; j < 4; ++j) {
        Bh[j] = *(const f16x8*)(bb_hi + (size_t)j * 16 * KK + kc);
        Bl[j] = *(const f16x8*)(bb_lo + (size_t)j * 16 * KK + kc);
      }

      // z for this lane's row: 32 elems = 4 x f16x8 (v_pk_mul_f16)
      const f16x8* xr = (const f16x8*)(xnr + qc * 32);
#pragma unroll
      for (int b = 0; b < 4; ++b) {
        const f16x8 zv = xb * xr[b];
        *(f16x8*)&zhi[nrow % 1 * 0 + (t * 40) + b * 8] = zv;  // row t of block
      }
      __builtin_amdgcn_wave_barrier();  // pin write->read order (no-op inst)

      f16x8 Ah[4];
#pragma unroll
      for (int i = 0; i < 4; ++i) Ah[i] = *(const f16x8*)&zhi[aoff[i]];
      __builtin_amdgcn_wave_barrier();  // pin read before next iter's writes

#pragma unroll
      for (int j = 0; j < 4; ++j)
#pragma unroll
        for (int i = 0; i < 4; ++i)
          acc[i][j] = __builtin_amdgcn_mfma_f32_16x16x32_f16(Ah[i], Bh[j], acc[i][j], 0, 0, 0);
#pragma unroll
      for (int j = 0; j < 4; ++j)
#pragma unroll
        for (int i = 0; i < 4; ++i)
          acc[i][j] = __builtin_amdgcn_mfma_f32_16x16x32_f16(Ah[i], Bl[j], acc[i][j], 0, 0, 0);
    }
  }

#pragma unroll
  for (int i = 0; i < 4; ++i)
#pragma unroll
    for (int j = 0; j < 4; ++j) {
      const int row = n0 + w * 64 + i * 16 + (l >> 4) * 4;
      const int col = h0 + j * 16 + (l & 15);
#pragma unroll
      for (int r = 0; r < 4; ++r)
        atomicAdd(&xout[(size_t)(row + r) * HD + col], acc[i][j][r]);
    }
}

// ---------------------------------------------------------------------------
// K23: xt[k][n][d] = sum_h (x[n][h]+b[h]) * (Wthi+Wtlo)[k*64+d][h]
// 2-pass fp16 MFMA, BK=32; bias+cvt fused in A-stage; u/v dots in epilogue.
// ---------------------------------------------------------------------------
__global__ __launch_bounds__(256) void k23_xt(
    const float* __restrict__ x, const float* __restrict__ bb,
    const f16* __restrict__ Wthi, const f16* __restrict__ Wtlo,
    const float* __restrict__ av, float* __restrict__ xt,
    float* __restrict__ ssrc, float* __restrict__ sdst) {
  __shared__ f16 ah[64 * 40];
  __shared__ f16 bh[128 * 32];
  __shared__ f16 bl[128 * 32];
  __shared__ float red1[2][64][17];
  __shared__ float red2[2][64][17];
  const int t = threadIdx.x;
  const int n0 = blockIdx.x * 64;
  const int c0 = blockIdx.y * 128;
  const int l = t & 63, w = t >> 6;
  const int wn = (w & 1) * 32, wcc = (w >> 1) * 64;

  int aoff[2], boff[4];
#pragma unroll
  for (int i = 0; i < 2; ++i)
    aoff[i] = (wn + i * 16 + (l & 15)) * 40 + (l >> 4) * 8;
#pragma unroll
  for (int j = 0; j < 4; ++j) {
    const int hr = wcc + j * 16 + (l & 15);
    boff[j] = hr * 32 + (((l >> 4) ^ ((hr ^ (hr >> 2)) & 3)) * 8);
  }

  f32x4 acc[2][4];
#pragma unroll
  for (int i = 0; i < 2; ++i)
#pragma unroll
    for (int j = 0; j < 4; ++j) acc[i][j] = (f32x4)0.f;

  for (int kc = 0; kc < HD; kc += 32) {
    __syncthreads();
    {
      const int row = t >> 2, sg = t & 3;
      const float* xr = &x[(size_t)(n0 + row) * HD + kc + sg * 8];
      const float4 xa = ((const float4*)xr)[0];
      const float4 xbv = ((const float4*)xr)[1];
      const float4 ba = *(const float4*)&bb[kc + sg * 8];
      const float4 bv = *(const float4*)&bb[kc + sg * 8 + 4];
      f16x8 o;
      o[0] = (f16)(xa.x + ba.x); o[1] = (f16)(xa.y + ba.y);
      o[2] = (f16)(xa.z + ba.z); o[3] = (f16)(xa.w + ba.w);
      o[4] = (f16)(xbv.x + bv.x); o[5] = (f16)(xbv.y + bv.y);
      o[6] = (f16)(xbv.z + bv.z); o[7] = (f16)(xbv.w + bv.w);
      *(f16x8*)&ah[row * 40 + sg * 8] = o;
    }
#pragma unroll
    for (int g = 0; g < 2; ++g) {
      const int slot = g * 256 + t;
      const int col = slot >> 2, ps = slot & 3;
      const int ls = ps ^ ((col ^ (col >> 2)) & 3);
      *(uint4*)&bh[col * 32 + ps * 8] =
          *(const uint4*)&Wthi[(size_t)(c0 + col) * HD + kc + ls * 8];
      *(uint4*)&bl[col * 32 + ps * 8] =
          *(const uint4*)&Wtlo[(size_t)(c0 + col) * HD + kc + ls * 8];
    }
    __syncthreads();
    f16x8 Af[2];
#pragma unroll
    for (int i = 0; i < 2; ++i) Af[i] = *(const f16x8*)&ah[aoff[i]];
#pragma unroll
    for (int j = 0; j < 4; ++j) {
      const f16x8 Bh = *(const f16x8*)&bh[boff[j]];
      const f16x8 Bl = *(const f16x8*)&bl[boff[j]];
#pragma unroll
      for (int i = 0; i < 2; ++i)
        acc[i][j] = __builtin_amdgcn_mfma_f32_16x16x32_f16(Af[i], Bh, acc[i][j], 0, 0, 0);
#pragma unroll
      for (int i = 0; i < 2; ++i)
        acc[i][j] = __builtin_amdgcn_mfma_f32_16x16x32_f16(Af[i], Bl, acc[i][j], 0, 0, 0);
    }
  }

  const int hh = w >> 1;
  const int khead = (c0 >> 6) + hh;
  float a1v[4], a2v[4];
#pragma unroll
  for (int j = 0; j < 4; ++j) {
    const int d = j * 16 + (l & 15);
    a1v[j] = av[khead * (2 * DD) + d];
    a2v[j] = av[khead * (2 * DD) + DD + d];
  }

#pragma unroll
  for (int i = 0; i < 2; ++i)
#pragma unroll
    for (int r = 0; r < 4; ++r) {
      const int rowl = wn + i * 16 + (l >> 4) * 4 + r;
      float p1 = 0.f, p2 = 0.f;
#pragma unroll
      for (int j = 0; j < 4; ++j) {
        p1 += acc[i][j][r] * a1v[j];
        p2 += acc[i][j][r] * a2v[j];
      }
      red1[hh][rowl][l & 15] = p1;
      red2[hh][rowl][l & 15] = p2;
    }

#pragma unroll
  for (int i = 0; i < 2; ++i)
#pragma unroll
    for (int j = 0; j < 4; ++j) {
      const int row = n0 + wn + i * 16 + (l >> 4) * 4;
      const int colg = c0 + wcc + j * 16 + (l & 15);
      const int k = colg >> 6, d = colg & 63;
#pragma unroll
      for (int r = 0; r < 4; ++r)
        xt[((size_t)(k * NN + row + r)) * DD + d] = acc[i][j][r];
    }

  __syncthreads();
  {
    const int hh2 = t >> 7;
    const int which = (t >> 6) & 1;
    const int row = t & 63;
    const float* rp = which ? &red2[hh2][row][0] : &red1[hh2][row][0];
    float s = 0.f;
#pragma unroll
    for (int g = 0; g < 16; ++g) s += rp[g];
    const int kk = (c0 >> 6) + hh2;
    if (which) sdst[kk * NN + n0 + row] = s;
    else ssrc[kk * NN + n0 + row] = s;
  }
}

// ---------------------------------------------------------------------------
// K4a: rank-and-scatter "sort" (exact total order via packed u64 keys)
// ---------------------------------------------------------------------------
__global__ __launch_bounds__(256) void k4_rank(
    const float* __restrict__ sdst, float* __restrict__ vsorted,
    int* __restrict__ perm) {
  __shared__ u64 kv[4096];
  const int k = blockIdx.y, t = threadIdx.x;
  for (int i = t; i < 4096; i += 256) {
    const uint u = __float_as_uint(sdst[k * NN + i]);
    const uint key = (u & 0x80000000u) ? ~u : (u | 0x80000000u);
    kv[i] = ((u64)key << 32) | (uint)i;
  }
  __syncthreads();
  const int m = blockIdx.x * 256 + t;
  const u64 my = kv[m];
  int cnt = 0;
#pragma unroll 16
  for (int j = 0; j < 4096; ++j) cnt += (kv[j] < my) ? 1 : 0;
  const uint key = (uint)(my >> 32);
  const uint u = (key & 0x80000000u) ? (key ^ 0x80000000u) : ~key;
  vsorted[k * NN + cnt] = __uint_as_float(u);
  perm[k * NN + cnt] = (int)(my & 0xFFFFFFFFu);
}

// ---------------------------------------------------------------------------
// K4b: per-(head,chunk) sums; LDS-staged gather + shared exp precompute.
// ---------------------------------------------------------------------------
__global__ __launch_bounds__(64) void k4b_chunksum(
    const float* __restrict__ vs, const int* __restrict__ perm,
    const float* __restrict__ xt, float* __restrict__ Chi, float* __restrict__ Clo) {
  __shared__ float rows[64][64];
  __shared__ float eh[64], el[64];
  const int c = blockIdx.x, k = blockIdx.y, t = threadIdx.x;
  const int base = k * NN + c * 64;
  {
    const float v = vs[base + t];
    eh[t] = __expf(v);
    el[t] = __expf(0.2f * v);
  }
#pragma unroll
  for (int r = 0; r < 16; ++r) {
    const int i = r * 4 + (t >> 4);
    const int p = perm[base + i];
    *(float4*)&rows[i][(t & 15) * 4] =
        *(const float4*)&xt[((size_t)(k * NN + p)) * DD + (t & 15) * 4];
  }
  __syncthreads();
  float shi = 0.f, slo = 0.f, whs = 0.f, wls = 0.f;
#pragma unroll 8
  for (int i = 0; i < 64; ++i) {
    const float val = rows[i][t];
    shi += eh[i] * val; slo += el[i] * val;
    whs += eh[i]; wls += el[i];
  }
  const int cb = (k * 64 + c) * 65;
  Chi[cb + t] = shi;
  Clo[cb + t] = slo;
  if (t == 0) { Chi[cb + 64] = whs; Clo[cb + 64] = wls; }
}

// ---------------------------------------------------------------------------
// K4d: expand to per-position prefix/suffix arrays; chunk-scan in-block.
// ---------------------------------------------------------------------------
__global__ __launch_bounds__(64) void k4d_expand(
    const float* __restrict__ vs, const int* __restrict__ perm,
    const float* __restrict__ xt, const float* __restrict__ Chi,
    const float* __restrict__ Clo, float* __restrict__ Phi,
    float* __restrict__ Plo) {
  __shared__ float schi[64 * 65];
  __shared__ float sclo[64 * 65];
  __shared__ float rows[64][64];
  __shared__ float eh[64], el[64];
  const int c = blockIdx.x, k = blockIdx.y, t = threadIdx.x;
  const int base = k * NN + c * 64;
  for (int idx = t; idx < 4160; idx += 64) {
    schi[idx] = Chi[k * 4160 + idx];
    sclo[idx] = Clo[k * 4160 + idx];
  }
  {
    const float v = vs[base + t];
    eh[t] = __expf(v);
    el[t] = __expf(0.2f * v);
  }
#pragma unroll
  for (int r = 0; r < 16; ++r) {
    const int i = r * 4 + (t >> 4);
    const int p = perm[base + i];
    *(float4*)&rows[i][(t & 15) * 4] =
        *(const float4*)&xt[((size_t)(k * NN + p)) * DD + (t & 15) * 4];
  }
  __syncthreads();

  float run = 0.f, wrun = 0.f;
  for (int cc = 0; cc < c; ++cc) {
    run += sclo[cc * 65 + t];
    wrun += sclo[cc * 65 + 64];
  }
  float runS = 0.f, wrunS = 0.f;
  for (int cc = c + 1; cc < 64; ++cc) {
    runS += schi[cc * 65 + t];
    wrunS += schi[cc * 65 + 64];
  }

  for (int i = 0; i < 64; ++i) {
    const size_t rb = ((size_t)(k * 4097) + c * 64 + i) * 65;
    Plo[rb + t] = run;
    if (t == 0) Plo[rb + 64] = wrun;
    run += el[i] * rows[i][t];
    wrun += el[i];
  }
  if (c == 63) {
    const size_t rb = ((size_t)(k * 4097) + 4096) * 65;
    Plo[rb + t] = run;
    if (t == 0) Plo[rb + 64] = wrun;
  }
  for (int i = 63; i >= 0; --i) {
    runS += eh[i] * rows[i][t];
    wrunS += eh[i];
    const size_t rb = ((size_t)(k * 4097) + c * 64 + i) * 65;
    Phi[rb + t] = runS;
    if (t == 0) Phi[rb + 64] = wrunS;
  }
  if (c == 63) {
    const size_t rb = ((size_t)(k * 4097) + 4096) * 65;
    Phi[rb + t] = 0.f;
    if (t == 0) Phi[rb + 64] = 0.f;
  }
}

// ---------------------------------------------------------------------------
// K6: per query: LDS binary search + combine + tanh. 16 queries/block.
// ---------------------------------------------------------------------------
__global__ __launch_bounds__(256) void k6_final(
    const float* __restrict__ ssrc, const float* __restrict__ vsorted,
    const float* __restrict__ Phi, const float* __restrict__ Plo,
    float* __restrict__ out) {
  __shared__ float vsh[4096];
  __shared__ int posSh[16];
  const int t = threadIdx.x;
  const int q0 = blockIdx.x * 16;
  const int k = q0 >> 12;
  for (int idx = t; idx < 1024; idx += 256)
    *(float4*)&vsh[idx * 4] = *(const float4*)&vsorted[k * NN + idx * 4];
  __syncthreads();
  if (t < 16) {
    const float thr = -ssrc[q0 + t];
    int lo = 0, hi = 4096;
    while (lo < hi) {
      const int mid = (lo + hi) >> 1;
      if (vsh[mid] < thr) lo = mid + 1; else hi = mid;
    }
    posSh[t] = lo;
  }
  __syncthreads();
  const int d = t & 63;
#pragma unroll
  for (int qq = 0; qq < 4; ++qq) {
    const int ql = qq * 4 + (t >> 6);
    const int qi = q0 + ql;
    const int n = qi & 4095;
    const float u = ssrc[qi];
    const size_t rb = ((size_t)(k * 4097) + posSh[ql]) * 65;
    const float eu = __expf(u), el = __expf(0.2f * u);
    const float num = eu * Phi[rb + d] + el * Plo[rb + d];
    const float den = eu * Phi[rb + 64] + el * Plo[rb + 64];
    out[(size_t)n * (KH * DD) + k * DD + d] = tanhf(num / den);
  }
}

extern "C" void kernel_launch(void* const* d_in, const int* in_sizes, int n_in,
                              void* d_out, int out_size, void* d_ws, size_t ws_size,
                              hipStream_t stream) {
  const float* xp = (const float*)d_in[0];
  const float* xn = (const float*)d_in[1];
  const float* W = (const float*)d_in[2];
  const float* bb = (const float*)d_in[3];
  const float* Wt = (const float*)d_in[4];
  const float* av = (const float*)d_in[5];
  float* out = (float*)d_out;

  char* ws = (char*)d_ws;
  // Phi/Plo overlay the W splits (temporally disjoint).
  f16* Whi    = (f16*)(ws);                       // 8 MB
  f16* Wlo    = (f16*)(ws + 8388608);             // 8 MB
  float* Phi  = (float*)(ws);                     // 8.52 MB (overlay)
  float* Plo  = (float*)(ws + 8522240);           // 8.52 MB (overlay)
  float* x    = (float*)(ws + 17044480);          // 4 MB
  float* xt   = (float*)(ws + 21238784);          // 8 MB
  f16* Wthi   = (f16*)(ws + 31724544);            // 256 KB
  f16* Wtlo   = (f16*)(ws + 31986688);            // 256 KB
  float* ssrc = (float*)(ws + 32248832);          // 128 KB
  float* sdst = (float*)(ws + 32379904);          // 128 KB
  float* vsort= (float*)(ws + 32510976);          // 128 KB
  int*   perm = (int*)  (ws + 32642048);          // 128 KB
  float* Chi  = (float*)(ws + 32773120);          // 133 KB
  float* Clo  = (float*)(ws + 32906240);          // 133 KB
  f16* xnh    = (f16*)(ws + 33039360);            // 1 MB
  f16* xph    = (f16*)(ws + 34087936);            // 1 MB -> ends ~35.1 MB

  k0_split2<<<(HD * PP * QQ + KH * DD * HD) / 1024, 256, 0, stream>>>(
      W, Wt, xn, xp, Whi, Wlo, Wthi, Wtlo, xnh, xph, x);
  k1_bilinear<<<dim3(NN / 256, 16, 4), 256, 0, stream>>>(xph, xnh, Whi, Wlo, x);
  k23_xt<<<dim3(NN / 64, 4), 256, 0, stream>>>(x, bb, Wthi, Wtlo, av, xt, ssrc, sdst);
  k4_rank<<<dim3(16, KH), 256, 0, stream>>>(sdst, vsort, perm);
  k4b_chunksum<<<dim3(64, KH), 64, 0, stream>>>(vsort, perm, xt, Chi, Clo);
  k4d_expand<<<dim3(64, KH), 64, 0, stream>>>(vsort, perm, xt, Chi, Clo, Phi, Plo);
  k6_final<<<(KH * NN) / 16, 256, 0, stream>>>(ssrc, vsort, Phi, Plo, out);
}

// Round 14
// 309.066 us; speedup vs baseline: 1.1790x; 1.1790x over previous
//
#include <hip/hip_runtime.h>
#include <hip/hip_bf16.h>

typedef unsigned short ushort;
typedef unsigned int uint;
typedef unsigned long long u64;
typedef _Float16 f16;

#define NN 4096
#define PP 128
#define QQ 128
#define HD 256
#define KH 8
#define DD 64
#define KK 16384  // P*Q

typedef _Float16 f16x2 __attribute__((ext_vector_type(2)));
typedef _Float16 f16x4 __attribute__((ext_vector_type(4)));
typedef _Float16 f16x8 __attribute__((ext_vector_type(8)));
typedef __fp16 fp16x2 __attribute__((ext_vector_type(2)));  // cvt_pkrtz return type
typedef float f32x4 __attribute__((ext_vector_type(4)));

__device__ inline void async_lds16(const void* g, void* l) {
  __builtin_amdgcn_global_load_lds(
      (const __attribute__((address_space(1))) unsigned int*)g,
      (__attribute__((address_space(3))) unsigned int*)l, 16, 0, 0);
}

// ---------------------------------------------------------------------------
// K0: split W and Wt fp32 -> f16 hi + f16 lo; also zero the x accumulator.
// ---------------------------------------------------------------------------
__global__ __launch_bounds__(256) void k0_split2(
    const float* __restrict__ W, const float* __restrict__ Wt,
    f16* __restrict__ hiW, f16* __restrict__ loW,
    f16* __restrict__ hiT, f16* __restrict__ loT, float* __restrict__ xz) {
  const int tid = blockIdx.x * 256 + threadIdx.x;
  const int i = tid * 4;
  if (tid < (NN * HD) / 4)
    *(float4*)&xz[i] = make_float4(0.f, 0.f, 0.f, 0.f);
  const float* src;
  f16 *hi, *lo;
  int off;
  if (i < HD * PP * QQ) { src = W; hi = hiW; lo = loW; off = i; }
  else { src = Wt; hi = hiT; lo = loT; off = i - HD * PP * QQ; }
  const float4 w = *(const float4*)&src[off];
  const float wf[4] = {w.x, w.y, w.z, w.w};
  f16x4 hv, lv;
#pragma unroll
  for (int j = 0; j < 4; ++j) {
    const f16 h = (f16)wf[j];
    hv[j] = h;
    lv[j] = (f16)(wf[j] - (float)h);
  }
  *(f16x4*)&hi[off] = hv;
  *(f16x4*)&lo[off] = lv;
}

// ---------------------------------------------------------------------------
// K1: bilinear via 2-pass fp16 MFMA. Block 128n x 128h (256 thr, 4 waves of
// 64n x 64h), BK=32, K-split 32, h-split 2 -> grid (32,32,2) = 2048 blocks,
// 16 K-iterations each. Work-conservation: serial iter-rounds per CU =
// (8 total blocks / ~4 concurrent) x 16 = 32 vs R11's (4/2.6)x32 = 49.
// W logical traffic unchanged at 512 MB (K-split partitions, not replicates).
// ---------------------------------------------------------------------------
__global__ __launch_bounds__(256, 4) void k1_bilinear(
    const float* __restrict__ xp, const float* __restrict__ xn,
    const f16* __restrict__ Whi, const f16* __restrict__ Wlo,
    float* __restrict__ xout) {
  __shared__ f16 whi[128 * 32];   // [h][k], XOR-swizzled 16B segs (8 KB)
  __shared__ f16 wlo[128 * 32];   // 8 KB
  __shared__ f16 zhi[128 * 40];   // [n][k] padded 32->40 (10 KB)
  __shared__ float xpt[4][128];   // 2 KB

  const int t = threadIdx.x;
  const int n0 = blockIdx.x * 128;
  const int kb = blockIdx.y * 512;        // 512-wide K chunk
  const int h0 = blockIdx.z * 128;
  const int pb = kb >> 7;                 // 4 p values per block

  for (int idx = t; idx < 512; idx += 256) {
    const int p = idx & 3, n = idx >> 2;
    xpt[p][n] = xp[(size_t)(n0 + n) * PP + pb + p];
  }

  const int l = t & 63, w = t >> 6;
  const int wr = (w >> 1) * 64, wc = (w & 1) * 64;

  int aoff[4], boff[4];
#pragma unroll
  for (int i = 0; i < 4; ++i)
    aoff[i] = (wr + i * 16 + (l & 15)) * 40 + (l >> 4) * 8;
#pragma unroll
  for (int j = 0; j < 4; ++j) {
    const int hr = wc + j * 16 + (l & 15);
    boff[j] = hr * 32 + (((l >> 4) ^ ((hr ^ (hr >> 2)) & 3)) * 8);
  }

  // W staging: 128 rows x 4 segs = 512 slots; 256 thr -> 2 row-groups of 64
  const int shb = t >> 2, seg = t & 3;
  int gsw[2];
#pragma unroll
  for (int g = 0; g < 2; ++g) {
    const int r = shb + 64 * g;
    gsw[g] = seg ^ ((r ^ (r >> 2)) & 3);
  }

  const int zn = t >> 1, zko = (t & 1) * 16;

  f32x4 acc[4][4];
#pragma unroll
  for (int i = 0; i < 4; ++i)
#pragma unroll
    for (int j = 0; j < 4; ++j) acc[i][j] = (f32x4)0.f;

  for (int c = 0; c < 16; ++c) {
    const int kc = kb + c * 32;
    const int pl = c >> 2;             // local p index (0..3)
    const int q0 = (c & 3) * 32;       // q base within row

    __syncthreads();  // previous step's fragment reads done (covers xpt too)

#pragma unroll
    for (int g = 0; g < 2; ++g) {
      const int r = shb + 64 * g;
      async_lds16(Whi + (size_t)(h0 + r) * KK + kc + gsw[g] * 8,
                  whi + r * 32 + seg * 8);
      async_lds16(Wlo + (size_t)(h0 + r) * KK + kc + gsw[g] * 8,
                  wlo + r * 32 + seg * 8);
    }

    // form Z tile: 128 rows x 32 k; 16 elems/thread, fp16 round via pkrtz
    {
      const float xpv = xpt[pl][zn];
      const float* xr = xn + (size_t)(n0 + zn) * QQ + q0 + zko;
      const float4 v0 = ((const float4*)xr)[0];
      const float4 v1 = ((const float4*)xr)[1];
      const float4 v2 = ((const float4*)xr)[2];
      const float4 v3 = ((const float4*)xr)[3];
      float zz[16] = {v0.x, v0.y, v0.z, v0.w, v1.x, v1.y, v1.z, v1.w,
                      v2.x, v2.y, v2.z, v2.w, v3.x, v3.y, v3.z, v3.w};
      union { uint u[8]; uint4 q[2]; } ph;
#pragma unroll
      for (int j = 0; j < 8; ++j) {
        union { fp16x2 h; uint u; } cv;
        cv.h = __builtin_amdgcn_cvt_pkrtz(xpv * zz[2 * j], xpv * zz[2 * j + 1]);
        ph.u[j] = cv.u;
      }
      const int zo = zn * 40 + zko;
      *(uint4*)&zhi[zo] = ph.q[0];
      *(uint4*)&zhi[zo + 8] = ph.q[1];
    }

    __syncthreads();  // W (vmcnt drained) + Z visible

    f16x8 Ah[4];
#pragma unroll
    for (int i = 0; i < 4; ++i) Ah[i] = *(const f16x8*)&zhi[aoff[i]];
#pragma unroll
    for (int j = 0; j < 4; ++j) {
      const f16x8 Bh = *(const f16x8*)&whi[boff[j]];
      const f16x8 Bl = *(const f16x8*)&wlo[boff[j]];
#pragma unroll
      for (int i = 0; i < 4; ++i)
        acc[i][j] = __builtin_amdgcn_mfma_f32_16x16x32_f16(Ah[i], Bh, acc[i][j], 0, 0, 0);
#pragma unroll
      for (int i = 0; i < 4; ++i)
        acc[i][j] = __builtin_amdgcn_mfma_f32_16x16x32_f16(Ah[i], Bl, acc[i][j], 0, 0, 0);
    }
  }

#pragma unroll
  for (int i = 0; i < 4; ++i)
#pragma unroll
    for (int j = 0; j < 4; ++j) {
      const int row = n0 + wr + i * 16 + (l >> 4) * 4;
      const int col = h0 + wc + j * 16 + (l & 15);
#pragma unroll
      for (int r = 0; r < 4; ++r)
        atomicAdd(&xout[(size_t)(row + r) * HD + col], acc[i][j][r]);
    }
}

// ---------------------------------------------------------------------------
// K23: xt[k][n][d] = sum_h (x[n][h]+b[h]) * (Wthi+Wtlo)[k*64+d][h]
// 2-pass fp16 MFMA, BK=32; bias+cvt fused in A-stage; u/v dots in epilogue.
// ---------------------------------------------------------------------------
__global__ __launch_bounds__(256) void k23_xt(
    const float* __restrict__ x, const float* __restrict__ bb,
    const f16* __restrict__ Wthi, const f16* __restrict__ Wtlo,
    const float* __restrict__ av, float* __restrict__ xt,
    float* __restrict__ ssrc, float* __restrict__ sdst) {
  __shared__ f16 ah[64 * 40];
  __shared__ f16 bh[128 * 32];
  __shared__ f16 bl[128 * 32];
  __shared__ float red1[2][64][17];
  __shared__ float red2[2][64][17];
  const int t = threadIdx.x;
  const int n0 = blockIdx.x * 64;
  const int c0 = blockIdx.y * 128;
  const int l = t & 63, w = t >> 6;
  const int wn = (w & 1) * 32, wcc = (w >> 1) * 64;

  int aoff[2], boff[4];
#pragma unroll
  for (int i = 0; i < 2; ++i)
    aoff[i] = (wn + i * 16 + (l & 15)) * 40 + (l >> 4) * 8;
#pragma unroll
  for (int j = 0; j < 4; ++j) {
    const int hr = wcc + j * 16 + (l & 15);
    boff[j] = hr * 32 + (((l >> 4) ^ ((hr ^ (hr >> 2)) & 3)) * 8);
  }

  f32x4 acc[2][4];
#pragma unroll
  for (int i = 0; i < 2; ++i)
#pragma unroll
    for (int j = 0; j < 4; ++j) acc[i][j] = (f32x4)0.f;

  for (int kc = 0; kc < HD; kc += 32) {
    __syncthreads();
    {
      const int row = t >> 2, sg = t & 3;
      const float* xr = &x[(size_t)(n0 + row) * HD + kc + sg * 8];
      const float4 xa = ((const float4*)xr)[0];
      const float4 xbv = ((const float4*)xr)[1];
      const float4 ba = *(const float4*)&bb[kc + sg * 8];
      const float4 bv = *(const float4*)&bb[kc + sg * 8 + 4];
      f16x8 o;
      o[0] = (f16)(xa.x + ba.x); o[1] = (f16)(xa.y + ba.y);
      o[2] = (f16)(xa.z + ba.z); o[3] = (f16)(xa.w + ba.w);
      o[4] = (f16)(xbv.x + bv.x); o[5] = (f16)(xbv.y + bv.y);
      o[6] = (f16)(xbv.z + bv.z); o[7] = (f16)(xbv.w + bv.w);
      *(f16x8*)&ah[row * 40 + sg * 8] = o;
    }
#pragma unroll
    for (int g = 0; g < 2; ++g) {
      const int slot = g * 256 + t;
      const int col = slot >> 2, ps = slot & 3;
      const int ls = ps ^ ((col ^ (col >> 2)) & 3);
      *(uint4*)&bh[col * 32 + ps * 8] =
          *(const uint4*)&Wthi[(size_t)(c0 + col) * HD + kc + ls * 8];
      *(uint4*)&bl[col * 32 + ps * 8] =
          *(const uint4*)&Wtlo[(size_t)(c0 + col) * HD + kc + ls * 8];
    }
    __syncthreads();
    f16x8 Af[2];
#pragma unroll
    for (int i = 0; i < 2; ++i) Af[i] = *(const f16x8*)&ah[aoff[i]];
#pragma unroll
    for (int j = 0; j < 4; ++j) {
      const f16x8 Bh = *(const f16x8*)&bh[boff[j]];
      const f16x8 Bl = *(const f16x8*)&bl[boff[j]];
#pragma unroll
      for (int i = 0; i < 2; ++i)
        acc[i][j] = __builtin_amdgcn_mfma_f32_16x16x32_f16(Af[i], Bh, acc[i][j], 0, 0, 0);
#pragma unroll
      for (int i = 0; i < 2; ++i)
        acc[i][j] = __builtin_amdgcn_mfma_f32_16x16x32_f16(Af[i], Bl, acc[i][j], 0, 0, 0);
    }
  }

  const int hh = w >> 1;
  const int khead = (c0 >> 6) + hh;
  float a1v[4], a2v[4];
#pragma unroll
  for (int j = 0; j < 4; ++j) {
    const int d = j * 16 + (l & 15);
    a1v[j] = av[khead * (2 * DD) + d];
    a2v[j] = av[khead * (2 * DD) + DD + d];
  }

#pragma unroll
  for (int i = 0; i < 2; ++i)
#pragma unroll
    for (int r = 0; r < 4; ++r) {
      const int rowl = wn + i * 16 + (l >> 4) * 4 + r;
      float p1 = 0.f, p2 = 0.f;
#pragma unroll
      for (int j = 0; j < 4; ++j) {
        p1 += acc[i][j][r] * a1v[j];
        p2 += acc[i][j][r] * a2v[j];
      }
      red1[hh][rowl][l & 15] = p1;
      red2[hh][rowl][l & 15] = p2;
    }

#pragma unroll
  for (int i = 0; i < 2; ++i)
#pragma unroll
    for (int j = 0; j < 4; ++j) {
      const int row = n0 + wn + i * 16 + (l >> 4) * 4;
      const int colg = c0 + wcc + j * 16 + (l & 15);
      const int k = colg >> 6, d = colg & 63;
#pragma unroll
      for (int r = 0; r < 4; ++r)
        xt[((size_t)(k * NN + row + r)) * DD + d] = acc[i][j][r];
    }

  __syncthreads();
  {
    const int hh2 = t >> 7;
    const int which = (t >> 6) & 1;
    const int row = t & 63;
    const float* rp = which ? &red2[hh2][row][0] : &red1[hh2][row][0];
    float s = 0.f;
#pragma unroll
    for (int g = 0; g < 16; ++g) s += rp[g];
    const int kk = (c0 >> 6) + hh2;
    if (which) sdst[kk * NN + n0 + row] = s;
    else ssrc[kk * NN + n0 + row] = s;
  }
}

// ---------------------------------------------------------------------------
// K4a: rank-and-scatter "sort" (exact total order via packed u64 keys)
// ---------------------------------------------------------------------------
__global__ __launch_bounds__(256) void k4_rank(
    const float* __restrict__ sdst, float* __restrict__ vsorted,
    int* __restrict__ perm) {
  __shared__ u64 kv[4096];
  const int k = blockIdx.y, t = threadIdx.x;
  for (int i = t; i < 4096; i += 256) {
    const uint u = __float_as_uint(sdst[k * NN + i]);
    const uint key = (u & 0x80000000u) ? ~u : (u | 0x80000000u);
    kv[i] = ((u64)key << 32) | (uint)i;
  }
  __syncthreads();
  const int m = blockIdx.x * 256 + t;
  const u64 my = kv[m];
  int cnt = 0;
#pragma unroll 16
  for (int j = 0; j < 4096; ++j) cnt += (kv[j] < my) ? 1 : 0;
  const uint key = (uint)(my >> 32);
  const uint u = (key & 0x80000000u) ? (key ^ 0x80000000u) : ~key;
  vsorted[k * NN + cnt] = __uint_as_float(u);
  perm[k * NN + cnt] = (int)(my & 0xFFFFFFFFu);
}

// ---------------------------------------------------------------------------
// K4b: per-(head,chunk) sums; LDS-staged gather + shared exp precompute.
// ---------------------------------------------------------------------------
__global__ __launch_bounds__(64) void k4b_chunksum(
    const float* __restrict__ vs, const int* __restrict__ perm,
    const float* __restrict__ xt, float* __restrict__ Chi, float* __restrict__ Clo) {
  __shared__ float rows[64][64];
  __shared__ float eh[64], el[64];
  const int c = blockIdx.x, k = blockIdx.y, t = threadIdx.x;
  const int base = k * NN + c * 64;
  {
    const float v = vs[base + t];
    eh[t] = __expf(v);
    el[t] = __expf(0.2f * v);
  }
#pragma unroll
  for (int r = 0; r < 16; ++r) {
    const int i = r * 4 + (t >> 4);
    const int p = perm[base + i];
    *(float4*)&rows[i][(t & 15) * 4] =
        *(const float4*)&xt[((size_t)(k * NN + p)) * DD + (t & 15) * 4];
  }
  __syncthreads();
  float shi = 0.f, slo = 0.f, whs = 0.f, wls = 0.f;
#pragma unroll 8
  for (int i = 0; i < 64; ++i) {
    const float val = rows[i][t];
    shi += eh[i] * val; slo += el[i] * val;
    whs += eh[i]; wls += el[i];
  }
  const int cb = (k * 64 + c) * 65;
  Chi[cb + t] = shi;
  Clo[cb + t] = slo;
  if (t == 0) { Chi[cb + 64] = whs; Clo[cb + 64] = wls; }
}

// ---------------------------------------------------------------------------
// K4d: expand to per-position prefix/suffix arrays; chunk-scan in-block.
// ---------------------------------------------------------------------------
__global__ __launch_bounds__(64) void k4d_expand(
    const float* __restrict__ vs, const int* __restrict__ perm,
    const float* __restrict__ xt, const float* __restrict__ Chi,
    const float* __restrict__ Clo, float* __restrict__ Phi,
    float* __restrict__ Plo) {
  __shared__ float schi[64 * 65];
  __shared__ float sclo[64 * 65];
  __shared__ float rows[64][64];
  __shared__ float eh[64], el[64];
  const int c = blockIdx.x, k = blockIdx.y, t = threadIdx.x;
  const int base = k * NN + c * 64;
  for (int idx = t; idx < 4160; idx += 64) {
    schi[idx] = Chi[k * 4160 + idx];
    sclo[idx] = Clo[k * 4160 + idx];
  }
  {
    const float v = vs[base + t];
    eh[t] = __expf(v);
    el[t] = __expf(0.2f * v);
  }
#pragma unroll
  for (int r = 0; r < 16; ++r) {
    const int i = r * 4 + (t >> 4);
    const int p = perm[base + i];
    *(float4*)&rows[i][(t & 15) * 4] =
        *(const float4*)&xt[((size_t)(k * NN + p)) * DD + (t & 15) * 4];
  }
  __syncthreads();

  float run = 0.f, wrun = 0.f;
  for (int cc = 0; cc < c; ++cc) {
    run += sclo[cc * 65 + t];
    wrun += sclo[cc * 65 + 64];
  }
  float runS = 0.f, wrunS = 0.f;
  for (int cc = c + 1; cc < 64; ++cc) {
    runS += schi[cc * 65 + t];
    wrunS += schi[cc * 65 + 64];
  }

  for (int i = 0; i < 64; ++i) {
    const size_t rb = ((size_t)(k * 4097) + c * 64 + i) * 65;
    Plo[rb + t] = run;
    if (t == 0) Plo[rb + 64] = wrun;
    run += el[i] * rows[i][t];
    wrun += el[i];
  }
  if (c == 63) {
    const size_t rb = ((size_t)(k * 4097) + 4096) * 65;
    Plo[rb + t] = run;
    if (t == 0) Plo[rb + 64] = wrun;
  }
  for (int i = 63; i >= 0; --i) {
    runS += eh[i] * rows[i][t];
    wrunS += eh[i];
    const size_t rb = ((size_t)(k * 4097) + c * 64 + i) * 65;
    Phi[rb + t] = runS;
    if (t == 0) Phi[rb + 64] = wrunS;
  }
  if (c == 63) {
    const size_t rb = ((size_t)(k * 4097) + 4096) * 65;
    Phi[rb + t] = 0.f;
    if (t == 0) Phi[rb + 64] = 0.f;
  }
}

// ---------------------------------------------------------------------------
// K6: per query: LDS binary search + combine + tanh. 16 queries/block.
// ---------------------------------------------------------------------------
__global__ __launch_bounds__(256) void k6_final(
    const float* __restrict__ ssrc, const float* __restrict__ vsorted,
    const float* __restrict__ Phi, const float* __restrict__ Plo,
    float* __restrict__ out) {
  __shared__ float vsh[4096];
  __shared__ int posSh[16];
  const int t = threadIdx.x;
  const int q0 = blockIdx.x * 16;
  const int k = q0 >> 12;
  for (int idx = t; idx < 1024; idx += 256)
    *(float4*)&vsh[idx * 4] = *(const float4*)&vsorted[k * NN + idx * 4];
  __syncthreads();
  if (t < 16) {
    const float thr = -ssrc[q0 + t];
    int lo = 0, hi = 4096;
    while (lo < hi) {
      const int mid = (lo + hi) >> 1;
      if (vsh[mid] < thr) lo = mid + 1; else hi = mid;
    }
    posSh[t] = lo;
  }
  __syncthreads();
  const int d = t & 63;
#pragma unroll
  for (int qq = 0; qq < 4; ++qq) {
    const int ql = qq * 4 + (t >> 6);
    const int qi = q0 + ql;
    const int n = qi & 4095;
    const float u = ssrc[qi];
    const size_t rb = ((size_t)(k * 4097) + posSh[ql]) * 65;
    const float eu = __expf(u), el = __expf(0.2f * u);
    const float num = eu * Phi[rb + d] + el * Plo[rb + d];
    const float den = eu * Phi[rb + 64] + el * Plo[rb + 64];
    out[(size_t)n * (KH * DD) + k * DD + d] = tanhf(num / den);
  }
}

extern "C" void kernel_launch(void* const* d_in, const int* in_sizes, int n_in,
                              void* d_out, int out_size, void* d_ws, size_t ws_size,
                              hipStream_t stream) {
  const float* xp = (const float*)d_in[0];
  const float* xn = (const float*)d_in[1];
  const float* W = (const float*)d_in[2];
  const float* bb = (const float*)d_in[3];
  const float* Wt = (const float*)d_in[4];
  const float* av = (const float*)d_in[5];
  float* out = (float*)d_out;

  char* ws = (char*)d_ws;
  // Phi/Plo overlay the W splits (temporally disjoint).
  f16* Whi    = (f16*)(ws);                       // 8 MB
  f16* Wlo    = (f16*)(ws + 8388608);             // 8 MB
  float* Phi  = (float*)(ws);                     // 8.52 MB (overlay)
  float* Plo  = (float*)(ws + 8522240);           // 8.52 MB (overlay)
  float* x    = (float*)(ws + 17044480);          // 4 MB
  float* xt   = (float*)(ws + 21238784);          // 8 MB
  f16* Wthi   = (f16*)(ws + 31724544);            // 256 KB
  f16* Wtlo   = (f16*)(ws + 31986688);            // 256 KB
  float* ssrc = (float*)(ws + 32248832);          // 128 KB
  float* sdst = (float*)(ws + 32379904);          // 128 KB
  float* vsort= (float*)(ws + 32510976);          // 128 KB
  int*   perm = (int*)  (ws + 32642048);          // 128 KB
  float* Chi  = (float*)(ws + 32773120);          // 133 KB
  float* Clo  = (float*)(ws + 32906240);          // 133 KB -> ends ~33.0 MB

  k0_split2<<<(HD * PP * QQ + KH * DD * HD) / 1024, 256, 0, stream>>>(
      W, Wt, Whi, Wlo, Wthi, Wtlo, x);
  k1_bilinear<<<dim3(NN / 128, 32, 2), 256, 0, stream>>>(xp, xn, Whi, Wlo, x);
  k23_xt<<<dim3(NN / 64, 4), 256, 0, stream>>>(x, bb, Wthi, Wtlo, av, xt, ssrc, sdst);
  k4_rank<<<dim3(16, KH), 256, 0, stream>>>(sdst, vsort, perm);
  k4b_chunksum<<<dim3(64, KH), 64, 0, stream>>>(vsort, perm, xt, Chi, Clo);
  k4d_expand<<<dim3(64, KH), 64, 0, stream>>>(vsort, perm, xt, Chi, Clo, Phi, Plo);
  k6_final<<<(KH * NN) / 16, 256, 0, stream>>>(ssrc, vsort, Phi, Plo, out);
}